// Round 2
// 398.835 us; speedup vs baseline: 1.1113x; 1.1113x over previous
//
#include <hip/hip_runtime.h>
#include <hip/hip_fp16.h>

// GCN 2-layer inference, N=100000, E=1600000, F_IN=100, H=128, C=47.
// R5: HYBRID precision after R4's absmax miss (1.367e-2 vs 1.258e-2 thr).
//  - layer-1 gathered table xw: fp8 e4m3 (HW cvt), 128B/row -> agg1 halved traffic
//  - layer-2 gathered table xw2: fp16 (error hits output directly; fp8 there
//    was the dominant error term), 48 halves = 96B/row, agg2 reads exact
//    dwords (24 lanes x 4B = 96B, always 2 lines/row; R3 read 128B/row).
//  Edge slots padded to multiple of 8 with dummy src=N -> all-zero row N;
//  branch-free gather loops. Col 47 of xw2 written as 0 (true pad).

typedef unsigned int uint32;
typedef float f32x2 __attribute__((ext_vector_type(2)));

constexpr int N    = 100000;
constexpr int E    = 1600000;
constexpr int FIN  = 100;
constexpr int HD   = 128;
constexpr int C    = 47;
constexpr int C48  = 48;
constexpr int EN_CAP = E + 8 * N;    // padded edge-slot upper bound
constexpr int SCAN_CHUNK = 2048;     // 256 threads * 8
constexpr int NB_SCAN = (N + SCAN_CHUNK - 1) / SCAN_CHUNK;  // 49

// ---------- fp8 helpers (hardware e4m3 on gfx950; self-consistent enc/dec) ----------

__device__ __forceinline__ uint32 pack_fp8x4(float x, float y, float z, float w) {
    int r = __builtin_amdgcn_cvt_pk_fp8_f32(x, y, 0, false);   // bytes 0,1
    r = __builtin_amdgcn_cvt_pk_fp8_f32(z, w, r, true);        // bytes 2,3
    return (uint32)r;
}

__device__ __forceinline__ void acc_fp8x4(uint32 v, float& a0, float& a1,
                                          float& a2, float& a3) {
    f32x2 lo = __builtin_amdgcn_cvt_pk_f32_fp8((int)v, false);
    f32x2 hi = __builtin_amdgcn_cvt_pk_f32_fp8((int)v, true);
    a0 += lo[0]; a1 += lo[1]; a2 += hi[0]; a3 += hi[1];
}

// ---------- CSR build ----------

__global__ void init_cnt(int* __restrict__ cnt) {
    int i = blockIdx.x * 256 + threadIdx.x;
    if (i < N) cnt[i] = 1;   // self loop occupies slot 0 of every node
}

// count degrees AND record each edge's slot within its dst node (>=1)
__global__ void count_pos(const int* __restrict__ dst, int* __restrict__ cnt,
                          int* __restrict__ epos) {
    int e = blockIdx.x * 256 + threadIdx.x;
    if (e < E) epos[e] = atomicAdd(&cnt[dst[e]], 1);
}

// sums CAPACITIES: cap = deg rounded up to multiple of 8
__global__ void scan_pass1(const int* __restrict__ cnt, int* __restrict__ partials) {
    int t = threadIdx.x, b = blockIdx.x;
    int base = b * SCAN_CHUNK + t * 8;
    int s = 0;
#pragma unroll
    for (int i = 0; i < 8; ++i) {
        int idx = base + i;
        if (idx < N) s += (cnt[idx] + 7) & ~7;
    }
    __shared__ int sm[256];
    sm[t] = s;
    __syncthreads();
    for (int off = 128; off > 0; off >>= 1) {
        if (t < off) sm[t] += sm[t + off];
        __syncthreads();
    }
    if (t == 0) partials[b] = sm[0];
}

__global__ void scan_pass2(const int* __restrict__ partials, int* __restrict__ pscan,
                           int* __restrict__ rowptr) {
    if (threadIdx.x == 0) {
        int run = 0;
        for (int i = 0; i < NB_SCAN; ++i) { pscan[i] = run; run += partials[i]; }
        rowptr[N] = run;   // padded total, <= E + 8N
    }
}

// rowptr (cap-based) + dinv + self-loop slot + pad slots (src=N -> zero row)
__global__ void scan_pass3(const int* __restrict__ cnt, const int* __restrict__ pscan,
                           int* __restrict__ rowptr, float* __restrict__ dinv,
                           int* __restrict__ ep) {
    int t = threadIdx.x, b = blockIdx.x;
    int base = b * SCAN_CHUNK + t * 8;
    int v[8];
    int s = 0;
#pragma unroll
    for (int i = 0; i < 8; ++i) {
        int idx = base + i;
        v[i] = (idx < N) ? cnt[idx] : 0;
        s += (v[i] + 7) & ~7;
    }
    __shared__ int sm[256];
    sm[t] = s;
    __syncthreads();
    for (int off = 1; off < 256; off <<= 1) {
        int tv = (t >= off) ? sm[t - off] : 0;
        __syncthreads();
        sm[t] += tv;
        __syncthreads();
    }
    int excl = sm[t] - s + pscan[b];
#pragma unroll
    for (int i = 0; i < 8; ++i) {
        int idx = base + i;
        if (idx < N) {
            int cap = (v[i] + 7) & ~7;
            rowptr[idx] = excl;
            ep[excl] = idx;                  // self loop at slot 0
            dinv[idx] = rsqrtf((float)v[i]); // true degree (>=1)
            for (int k = v[i]; k < cap; ++k) ep[excl + k] = N;  // pads -> zero row
            excl += cap;
        }
    }
}

// atomic-free scatter: slot was precomputed in count_pos
__global__ void scatter_edges(const int* __restrict__ ei, const int* __restrict__ rowptr,
                              const int* __restrict__ epos, int* __restrict__ ep) {
    int e = blockIdx.x * 256 + threadIdx.x;
    if (e < E) {
        int s = ei[e];
        int d = ei[E + e];
        ep[rowptr[d] + epos[e]] = s;
    }
}

// ---------- GEMM1: xw8[N+1,32 dwords] fp8 = dinv[n] * (x[N,100] @ W1[100,128]) ----------

__global__ __launch_bounds__(256) void gemm1(const float* __restrict__ x,
                                             const float* __restrict__ W1,
                                             const float* __restrict__ dinv,
                                             uint32* __restrict__ xw8) {
    __shared__ float sW[FIN * HD];     // 51.2 KB
    __shared__ float sX[64 * FIN];     // 25.6 KB
    int tx = threadIdx.x;
    size_t node0 = (size_t)blockIdx.x * 64;

    const float4* W4 = (const float4*)W1;
    for (int i = tx; i < FIN * HD / 4; i += 256) ((float4*)sW)[i] = W4[i];
    size_t base4 = node0 * FIN / 4;          // node0*100 divisible by 4
    const float4* x4 = (const float4*)x;
    for (int i = tx; i < 64 * FIN / 4; i += 256) {
        size_t g = base4 + i;
        ((float4*)sX)[i] = (g < (size_t)N * FIN / 4) ? x4[g]
                                                     : make_float4(0.f, 0.f, 0.f, 0.f);
    }
    __syncthreads();

    int col = (tx & 31) * 4;        // 0..124
    int nb  = (tx >> 5) * 8;        // 0..56
    float4 acc[8];
#pragma unroll
    for (int i = 0; i < 8; ++i) acc[i] = make_float4(0.f, 0.f, 0.f, 0.f);

    for (int k = 0; k < FIN; ++k) {
        float4 b = *(const float4*)&sW[k * HD + col];
#pragma unroll
        for (int i = 0; i < 8; ++i) {
            float a = sX[(nb + i) * FIN + k];
            acc[i].x = fmaf(a, b.x, acc[i].x);
            acc[i].y = fmaf(a, b.y, acc[i].y);
            acc[i].z = fmaf(a, b.z, acc[i].z);
            acc[i].w = fmaf(a, b.w, acc[i].w);
        }
    }
#pragma unroll
    for (int i = 0; i < 8; ++i) {
        size_t node = node0 + nb + i;
        if (node < (size_t)N) {
            float dv = dinv[node];
            xw8[node * 32 + (col >> 2)] =
                pack_fp8x4(acc[i].x * dv, acc[i].y * dv, acc[i].z * dv, acc[i].w * dv);
        } else if (node == (size_t)N) {
            xw8[node * 32 + (col >> 2)] = 0u;   // zero row for pad edges
        }
    }
}

// ---------- agg1: h[n] (fp16) = relu(b1 + dinv[n] * sum_j xw8[src_j]) ----------
// 2 edges per wave-load: lanes 0-31 even edge, lanes 32-63 odd edge; dword = 4 fp8 dims.

__global__ __launch_bounds__(256) void agg1(const uint32* __restrict__ xw8,
                                            const int* __restrict__ rowptr,
                                            const int* __restrict__ ep,
                                            const float* __restrict__ dinv,
                                            const float* __restrict__ b1,
                                            __half* __restrict__ h) {
    int node = blockIdx.x * 4 + (threadIdx.x >> 6);
    if (node >= N) return;
    int lane = threadIdx.x & 63;
    int hf = lane >> 5;      // which edge of the pair
    int q  = lane & 31;      // dword within 128B row -> dims q*4..q*4+3
    int beg = rowptr[node], end = rowptr[node + 1];   // cap, multiple of 8
    float a0 = 0.f, a1 = 0.f, a2 = 0.f, a3 = 0.f;
    for (int j = beg; j < end; j += 8) {
        int s0 = ep[j + hf];
        int s1 = ep[j + 2 + hf];
        int s2 = ep[j + 4 + hf];
        int s3 = ep[j + 6 + hf];
        uint32 v0 = xw8[(size_t)s0 * 32 + q];
        uint32 v1 = xw8[(size_t)s1 * 32 + q];
        uint32 v2 = xw8[(size_t)s2 * 32 + q];
        uint32 v3 = xw8[(size_t)s3 * 32 + q];
        acc_fp8x4(v0, a0, a1, a2, a3);
        acc_fp8x4(v1, a0, a1, a2, a3);
        acc_fp8x4(v2, a0, a1, a2, a3);
        acc_fp8x4(v3, a0, a1, a2, a3);
    }
    // combine the two edge-halves (same dims in both)
    a0 += __shfl_xor(a0, 32);
    a1 += __shfl_xor(a1, 32);
    a2 += __shfl_xor(a2, 32);
    a3 += __shfl_xor(a3, 32);
    if (hf == 0) {
        float dv = dinv[node];
        float4 bb = *(const float4*)&b1[q * 4];
        float r0 = fmaxf(fmaf(dv, a0, bb.x), 0.f);
        float r1 = fmaxf(fmaf(dv, a1, bb.y), 0.f);
        float r2 = fmaxf(fmaf(dv, a2, bb.z), 0.f);
        float r3 = fmaxf(fmaf(dv, a3, bb.w), 0.f);
        union { __half2 h2[2]; uint2 u; } p;
        p.h2[0] = __floats2half2_rn(r0, r1);
        p.h2[1] = __floats2half2_rn(r2, r3);
        *(uint2*)&h[(size_t)node * HD + q * 4] = p.u;
    }
}

// ---------- GEMM2: xw2h[N+1,48] fp16 = dinv[n] * (h[N,128] @ W2[128,47]), col47=0 ----------

__global__ __launch_bounds__(256) void gemm2(const __half2* __restrict__ hh2,
                                             const float* __restrict__ W2,
                                             const float* __restrict__ dinv,
                                             __half* __restrict__ xw2h) {
    __shared__ float sH[64 * 130];     // padded stride 130
    __shared__ float sW[HD * 48];      // padded to 48 cols (pad col = 0)
    int tx = threadIdx.x;
    size_t node0 = (size_t)blockIdx.x * 64;

    for (int i = tx; i < HD * 48; i += 256) {
        int k = i / 48, c = i - k * 48;
        sW[i] = (c < C) ? W2[k * C + c] : 0.f;
    }
    size_t base2 = node0 * 64;
    for (int i = tx; i < 64 * 64; i += 256) {
        size_t g = base2 + i;
        float2 f = (g < (size_t)N * 64) ? __half22float2(hh2[g]) : make_float2(0.f, 0.f);
        int row = i >> 6, c2 = (i & 63) * 2;
        sH[row * 130 + c2]     = f.x;
        sH[row * 130 + c2 + 1] = f.y;
    }
    __syncthreads();

    int c0 = (tx & 15) * 3;        // 0..45
    int nb = (tx >> 4) * 4;        // 0..60
    float acc[4][3] = {};
    for (int k = 0; k < HD; ++k) {
        float w0 = sW[k * 48 + c0];
        float w1 = sW[k * 48 + c0 + 1];
        float w2 = sW[k * 48 + c0 + 2];
#pragma unroll
        for (int i = 0; i < 4; ++i) {
            float a = sH[(nb + i) * 130 + k];
            acc[i][0] = fmaf(a, w0, acc[i][0]);
            acc[i][1] = fmaf(a, w1, acc[i][1]);
            acc[i][2] = fmaf(a, w2, acc[i][2]);
        }
    }
#pragma unroll
    for (int i = 0; i < 4; ++i) {
        size_t node = node0 + nb + i;
        if (node < (size_t)N) {
            float dv = dinv[node];
#pragma unroll
            for (int jj = 0; jj < 3; ++jj) {
                int c = c0 + jj;
                // col 47 gets 0 (sW pad col is 0) -> dv*0 = 0, true zero pad
                xw2h[node * C48 + c] = __float2half_rn(acc[i][jj] * dv);
            }
        } else if (node == (size_t)N) {
#pragma unroll
            for (int jj = 0; jj < 3; ++jj)
                xw2h[node * C48 + c0 + jj] = __float2half_rn(0.f);  // zero row for pads
        }
    }
}

// ---------- agg2: out[n] = b2 + dinv[n] * sum_j xw2[src_j] ----------
// dword (=half2) gather: 24 lanes cover one 96B row exactly; 2 edges per step.

__global__ __launch_bounds__(256) void agg2(const uint32* __restrict__ xw2d,
                                            const int* __restrict__ rowptr,
                                            const int* __restrict__ ep,
                                            const float* __restrict__ dinv,
                                            const float* __restrict__ b2,
                                            float* __restrict__ out) {
    int node = blockIdx.x * 4 + (threadIdx.x >> 6);
    if (node >= N) return;
    int lane = threadIdx.x & 63;
    int hf = lane >> 5;      // which edge of the pair
    int q  = lane & 31;      // dword within row (only q<24 valid)
    bool act = q < 24;
    int beg = rowptr[node], end = rowptr[node + 1];   // cap, multiple of 8
    float a0 = 0.f, a1 = 0.f;
    for (int j = beg; j < end; j += 8) {
        int s0 = ep[j + hf];
        int s1 = ep[j + 2 + hf];
        int s2 = ep[j + 4 + hf];
        int s3 = ep[j + 6 + hf];
        if (act) {
            uint32 v0 = xw2d[(size_t)s0 * 24 + q];
            uint32 v1 = xw2d[(size_t)s1 * 24 + q];
            uint32 v2 = xw2d[(size_t)s2 * 24 + q];
            uint32 v3 = xw2d[(size_t)s3 * 24 + q];
            float2 f;
            f = __half22float2(*(const __half2*)&v0); a0 += f.x; a1 += f.y;
            f = __half22float2(*(const __half2*)&v1); a0 += f.x; a1 += f.y;
            f = __half22float2(*(const __half2*)&v2); a0 += f.x; a1 += f.y;
            f = __half22float2(*(const __half2*)&v3); a0 += f.x; a1 += f.y;
        }
    }
    // combine the two edge-halves
    a0 += __shfl_xor(a0, 32);
    a1 += __shfl_xor(a1, 32);
    if (hf == 0 && act) {
        float dv = dinv[node];
        int c = q * 2;
        out[(size_t)node * C + c] = fmaf(dv, a0, b2[c]);
        if (c + 1 < C) out[(size_t)node * C + c + 1] = fmaf(dv, a1, b2[c + 1]);
    }
}

extern "C" void kernel_launch(void* const* d_in, const int* in_sizes, int n_in,
                              void* d_out, int out_size, void* d_ws, size_t ws_size,
                              hipStream_t stream) {
    const float* x  = (const float*)d_in[0];
    const int*   ei = (const int*)d_in[1];
    const float* W1 = (const float*)d_in[2];
    const float* b1 = (const float*)d_in[3];
    const float* W2 = (const float*)d_in[4];
    const float* b2 = (const float*)d_in[5];
    float* out = (float*)d_out;

    size_t off = 0;
    auto alloc = [&](size_t bytes) {
        void* p = (char*)d_ws + off;
        off += (bytes + 255) & ~(size_t)255;
        return p;
    };
    int*    cnt      = (int*)alloc((size_t)N * 4);
    int*    rowptr   = (int*)alloc((size_t)(N + 1) * 4);
    int*    epos     = (int*)alloc((size_t)E * 4);
    int*    partials = (int*)alloc(64 * 4);
    int*    pscan    = (int*)alloc(64 * 4);
    float*  dinv     = (float*)alloc((size_t)N * 4);
    int*    ep       = (int*)alloc((size_t)EN_CAP * 4);
    uint32* xw8      = (uint32*)alloc((size_t)(N + 1) * 32 * 4);   // fp8 [N+1][128]
    __half* hh       = (__half*)alloc((size_t)N * HD * 2);
    __half* xw2h     = (__half*)alloc((size_t)(N + 1) * C48 * 2);  // fp16 [N+1][48]
    (void)ws_size;

    int gN = (N + 255) / 256;
    int gE = (E + 255) / 256;

    init_cnt<<<gN, 256, 0, stream>>>(cnt);
    count_pos<<<gE, 256, 0, stream>>>(ei + E, cnt, epos);
    scan_pass1<<<NB_SCAN, 256, 0, stream>>>(cnt, partials);
    scan_pass2<<<1, 64, 0, stream>>>(partials, pscan, rowptr);
    scan_pass3<<<NB_SCAN, 256, 0, stream>>>(cnt, pscan, rowptr, dinv, ep);
    scatter_edges<<<gE, 256, 0, stream>>>(ei, rowptr, epos, ep);

    gemm1<<<(N + 63) / 64, 256, 0, stream>>>(x, W1, dinv, xw8);
    agg1<<<(N + 3) / 4, 256, 0, stream>>>(xw8, rowptr, ep, dinv, b1, hh);
    gemm2<<<(N + 63) / 64, 256, 0, stream>>>((const __half2*)hh, W2, dinv, xw2h);
    agg2<<<(N + 3) / 4, 256, 0, stream>>>((const uint32*)xw2h, rowptr, ep, dinv, b2, out);
}

// Round 4
// 367.051 us; speedup vs baseline: 1.2075x; 1.0866x over previous
//
#include <hip/hip_runtime.h>
#include <hip/hip_fp16.h>

// GCN 2-layer inference, N=100000, E=1600000, F_IN=100, H=128, C=47.
// R7 = R6 with compile fix (cvt_pkrtz returns __fp16 vector, not _Float16).
// GEMM occupancy + v_dot2 rewrite (gemm2 was #1 at 72us: 17% occupancy
// from 57.9KB LDS, VALUBusy 27% -> latency-bound).
//  - both GEMMs stage operands as fp16 half2 (k-pair interleaved) in LDS and
//    consume with v_dot2_f32_f16 (1 inst = 2 FMA): inner-loop inst count ~2x down
//  - gemm1 LDS 76.8->38.4 KB (4 blocks/CU), gemm2 57.9->29.2 KB (5 blocks/CU)
//  - agg1 (fp8 table) / agg2 (fp16 table) / CSR build unchanged from R5 (passed,
//    absmax 0.0078 vs thr 0.0126).

typedef unsigned int uint32;
typedef float f32x2 __attribute__((ext_vector_type(2)));
typedef __fp16 fp16x2 __attribute__((ext_vector_type(2)));
typedef _Float16 h2v __attribute__((ext_vector_type(2)));

constexpr int N    = 100000;
constexpr int E    = 1600000;
constexpr int FIN  = 100;
constexpr int HD   = 128;
constexpr int C    = 47;
constexpr int C48  = 48;
constexpr int EN_CAP = E + 8 * N;    // padded edge-slot upper bound
constexpr int SCAN_CHUNK = 2048;     // 256 threads * 8
constexpr int NB_SCAN = (N + SCAN_CHUNK - 1) / SCAN_CHUNK;  // 49

// ---------- fp8 / fp16 helpers ----------

__device__ __forceinline__ uint32 pack_fp8x4(float x, float y, float z, float w) {
    int r = __builtin_amdgcn_cvt_pk_fp8_f32(x, y, 0, false);   // bytes 0,1
    r = __builtin_amdgcn_cvt_pk_fp8_f32(z, w, r, true);        // bytes 2,3
    return (uint32)r;
}

__device__ __forceinline__ void acc_fp8x4(uint32 v, float& a0, float& a1,
                                          float& a2, float& a3) {
    f32x2 lo = __builtin_amdgcn_cvt_pk_f32_fp8((int)v, false);
    f32x2 hi = __builtin_amdgcn_cvt_pk_f32_fp8((int)v, true);
    a0 += lo[0]; a1 += lo[1]; a2 += hi[0]; a3 += hi[1];
}

__device__ __forceinline__ uint32 pk16(float a, float b) {
    union { fp16x2 h; uint32 u; } x;
    x.h = __builtin_amdgcn_cvt_pkrtz(a, b);    // v_cvt_pkrtz_f16_f32
    return x.u;
}

__device__ __forceinline__ float dot2f(uint32 a, uint32 b, float c) {
#if defined(__has_builtin) && __has_builtin(__builtin_amdgcn_fdot2)
    union { uint32 u; h2v h; } xa, xb; xa.u = a; xb.u = b;
    return __builtin_amdgcn_fdot2(xa.h, xb.h, c, false);
#else
    union { uint32 u; __half2 h; } xa, xb; xa.u = a; xb.u = b;
    float2 fa = __half22float2(xa.h), fb = __half22float2(xb.h);
    return fmaf(fa.y, fb.y, fmaf(fa.x, fb.x, c));
#endif
}

// ---------- CSR build ----------

__global__ void init_cnt(int* __restrict__ cnt) {
    int i = blockIdx.x * 256 + threadIdx.x;
    if (i < N) cnt[i] = 1;   // self loop occupies slot 0 of every node
}

__global__ void count_pos(const int* __restrict__ dst, int* __restrict__ cnt,
                          int* __restrict__ epos) {
    int e = blockIdx.x * 256 + threadIdx.x;
    if (e < E) epos[e] = atomicAdd(&cnt[dst[e]], 1);
}

// sums CAPACITIES: cap = deg rounded up to multiple of 8
__global__ void scan_pass1(const int* __restrict__ cnt, int* __restrict__ partials) {
    int t = threadIdx.x, b = blockIdx.x;
    int base = b * SCAN_CHUNK + t * 8;
    int s = 0;
#pragma unroll
    for (int i = 0; i < 8; ++i) {
        int idx = base + i;
        if (idx < N) s += (cnt[idx] + 7) & ~7;
    }
    __shared__ int sm[256];
    sm[t] = s;
    __syncthreads();
    for (int off = 128; off > 0; off >>= 1) {
        if (t < off) sm[t] += sm[t + off];
        __syncthreads();
    }
    if (t == 0) partials[b] = sm[0];
}

__global__ void scan_pass2(const int* __restrict__ partials, int* __restrict__ pscan,
                           int* __restrict__ rowptr) {
    if (threadIdx.x == 0) {
        int run = 0;
        for (int i = 0; i < NB_SCAN; ++i) { pscan[i] = run; run += partials[i]; }
        rowptr[N] = run;   // padded total, <= E + 8N
    }
}

// rowptr (cap-based) + dinv + self-loop slot + pad slots (src=N -> zero row)
__global__ void scan_pass3(const int* __restrict__ cnt, const int* __restrict__ pscan,
                           int* __restrict__ rowptr, float* __restrict__ dinv,
                           int* __restrict__ ep) {
    int t = threadIdx.x, b = blockIdx.x;
    int base = b * SCAN_CHUNK + t * 8;
    int v[8];
    int s = 0;
#pragma unroll
    for (int i = 0; i < 8; ++i) {
        int idx = base + i;
        v[i] = (idx < N) ? cnt[idx] : 0;
        s += (v[i] + 7) & ~7;
    }
    __shared__ int sm[256];
    sm[t] = s;
    __syncthreads();
    for (int off = 1; off < 256; off <<= 1) {
        int tv = (t >= off) ? sm[t - off] : 0;
        __syncthreads();
        sm[t] += tv;
        __syncthreads();
    }
    int excl = sm[t] - s + pscan[b];
#pragma unroll
    for (int i = 0; i < 8; ++i) {
        int idx = base + i;
        if (idx < N) {
            int cap = (v[i] + 7) & ~7;
            rowptr[idx] = excl;
            ep[excl] = idx;                  // self loop at slot 0
            dinv[idx] = rsqrtf((float)v[i]); // true degree (>=1)
            for (int k = v[i]; k < cap; ++k) ep[excl + k] = N;  // pads -> zero row
            excl += cap;
        }
    }
}

// atomic-free scatter: slot was precomputed in count_pos
__global__ void scatter_edges(const int* __restrict__ ei, const int* __restrict__ rowptr,
                              const int* __restrict__ epos, int* __restrict__ ep) {
    int e = blockIdx.x * 256 + threadIdx.x;
    if (e < E) {
        int s = ei[e];
        int d = ei[E + e];
        ep[rowptr[d] + epos[e]] = s;
    }
}

// ---------- GEMM1: xw8[N+1,32 dwords] fp8 = dinv[n] * (x[N,100] @ W1[100,128]) ----------
// fp16 operands in LDS, v_dot2 inner loop. K=100 = 50 exact k-pairs.
// sW layout [kk][c] half2(k=2kk,2kk+1): lane reads b128 (4 cols) -> conflict-free.
// sX layout [row][kk]: rows differ by 8 -> 8*50 mod 32 = 16, 2-way (free).

__global__ __launch_bounds__(256) void gemm1(const float* __restrict__ x,
                                             const float* __restrict__ W1,
                                             const float* __restrict__ dinv,
                                             uint32* __restrict__ xw8) {
    __shared__ uint32 sW[50 * 128];    // 25.6 KB
    __shared__ uint32 sX[64 * 50];     // 12.8 KB
    int tx = threadIdx.x;
    size_t node0 = (size_t)blockIdx.x * 64;

    for (int i = tx; i < 50 * 128; i += 256) {
        int kk = i >> 7, c = i & 127;
        sW[i] = pk16(W1[(2 * kk) * HD + c], W1[(2 * kk + 1) * HD + c]);
    }
    for (int i = tx; i < 64 * 50; i += 256) {
        int row = i / 50, kk = i - row * 50;
        size_t node = node0 + row;
        float2 ab = make_float2(0.f, 0.f);
        if (node < (size_t)N)
            ab = ((const float2*)(x + node * FIN))[kk];   // 8B aligned (400B rows)
        sX[i] = pk16(ab.x, ab.y);
    }
    __syncthreads();

    int col = (tx & 31) * 4;        // 0..124
    int nb  = (tx >> 5) * 8;        // 0..56
    float4 acc[8];
#pragma unroll
    for (int i = 0; i < 8; ++i) acc[i] = make_float4(0.f, 0.f, 0.f, 0.f);

    for (int kk = 0; kk < 50; ++kk) {
        uint4 w = *(const uint4*)&sW[kk * 128 + col];     // ds_read_b128
#pragma unroll
        for (int i = 0; i < 8; ++i) {
            uint32 a = sX[(nb + i) * 50 + kk];
            acc[i].x = dot2f(a, w.x, acc[i].x);
            acc[i].y = dot2f(a, w.y, acc[i].y);
            acc[i].z = dot2f(a, w.z, acc[i].z);
            acc[i].w = dot2f(a, w.w, acc[i].w);
        }
    }
#pragma unroll
    for (int i = 0; i < 8; ++i) {
        size_t node = node0 + nb + i;
        if (node < (size_t)N) {
            float dv = dinv[node];
            xw8[node * 32 + (col >> 2)] =
                pack_fp8x4(acc[i].x * dv, acc[i].y * dv, acc[i].z * dv, acc[i].w * dv);
        } else if (node == (size_t)N) {
            xw8[node * 32 + (col >> 2)] = 0u;   // zero row for pad edges
        }
    }
}

// ---------- agg1: h[n] (fp16) = relu(b1 + dinv[n] * sum_j xw8[src_j]) ----------

__global__ __launch_bounds__(256) void agg1(const uint32* __restrict__ xw8,
                                            const int* __restrict__ rowptr,
                                            const int* __restrict__ ep,
                                            const float* __restrict__ dinv,
                                            const float* __restrict__ b1,
                                            __half* __restrict__ h) {
    int node = blockIdx.x * 4 + (threadIdx.x >> 6);
    if (node >= N) return;
    int lane = threadIdx.x & 63;
    int hf = lane >> 5;      // which edge of the pair
    int q  = lane & 31;      // dword within 128B row -> dims q*4..q*4+3
    int beg = rowptr[node], end = rowptr[node + 1];   // cap, multiple of 8
    float a0 = 0.f, a1 = 0.f, a2 = 0.f, a3 = 0.f;
    for (int j = beg; j < end; j += 8) {
        int s0 = ep[j + hf];
        int s1 = ep[j + 2 + hf];
        int s2 = ep[j + 4 + hf];
        int s3 = ep[j + 6 + hf];
        uint32 v0 = xw8[(size_t)s0 * 32 + q];
        uint32 v1 = xw8[(size_t)s1 * 32 + q];
        uint32 v2 = xw8[(size_t)s2 * 32 + q];
        uint32 v3 = xw8[(size_t)s3 * 32 + q];
        acc_fp8x4(v0, a0, a1, a2, a3);
        acc_fp8x4(v1, a0, a1, a2, a3);
        acc_fp8x4(v2, a0, a1, a2, a3);
        acc_fp8x4(v3, a0, a1, a2, a3);
    }
    a0 += __shfl_xor(a0, 32);
    a1 += __shfl_xor(a1, 32);
    a2 += __shfl_xor(a2, 32);
    a3 += __shfl_xor(a3, 32);
    if (hf == 0) {
        float dv = dinv[node];
        float4 bb = *(const float4*)&b1[q * 4];
        float r0 = fmaxf(fmaf(dv, a0, bb.x), 0.f);
        float r1 = fmaxf(fmaf(dv, a1, bb.y), 0.f);
        float r2 = fmaxf(fmaf(dv, a2, bb.z), 0.f);
        float r3 = fmaxf(fmaf(dv, a3, bb.w), 0.f);
        union { __half2 h2[2]; uint2 u; } p;
        p.h2[0] = __floats2half2_rn(r0, r1);
        p.h2[1] = __floats2half2_rn(r2, r3);
        *(uint2*)&h[(size_t)node * HD + q * 4] = p.u;
    }
}

// ---------- GEMM2: xw2h[N+1,48] fp16 = dinv[n] * (h[N,128] @ W2[128,47]), col47=0 ----------
// fp16 operands in LDS, v_dot2. sW [kk][48] k-pair half2: lanes read 3m mod 32
// distinct banks. sH [row][66]: raw dword copy of hh (no cvt), rows 4 apart ->
// banks 8 apart. LDS 29.2 KB -> 5 blocks/CU (was 57.9 KB -> 2).

__global__ __launch_bounds__(256) void gemm2(const uint32* __restrict__ hh,
                                             const float* __restrict__ W2,
                                             const float* __restrict__ dinv,
                                             __half* __restrict__ xw2h) {
    __shared__ uint32 sW[64 * 48];     // 12.3 KB
    __shared__ uint32 sH[64 * 66];     // 16.9 KB (pad 66)
    int tx = threadIdx.x;
    size_t node0 = (size_t)blockIdx.x * 64;

    for (int i = tx; i < 64 * 48; i += 256) {
        int kk = i / 48, c = i - kk * 48;
        float a = 0.f, b = 0.f;
        if (c < C) {
            a = W2[(2 * kk) * C + c];
            b = W2[(2 * kk + 1) * C + c];
        }
        sW[i] = pk16(a, b);
    }
    for (int i = tx; i < 64 * 64; i += 256) {
        int row = i >> 6, kk = i & 63;
        size_t g = node0 * 64 + i;
        sH[row * 66 + kk] = (g < (size_t)N * 64) ? hh[g] : 0u;
    }
    __syncthreads();

    int c0 = (tx & 15) * 3;        // 0..45
    int nb = (tx >> 4) * 4;        // 0..60
    float acc[4][3] = {};
    for (int kk = 0; kk < 64; ++kk) {
        uint32 w0 = sW[kk * 48 + c0];
        uint32 w1 = sW[kk * 48 + c0 + 1];
        uint32 w2 = sW[kk * 48 + c0 + 2];
#pragma unroll
        for (int i = 0; i < 4; ++i) {
            uint32 a = sH[(nb + i) * 66 + kk];
            acc[i][0] = dot2f(a, w0, acc[i][0]);
            acc[i][1] = dot2f(a, w1, acc[i][1]);
            acc[i][2] = dot2f(a, w2, acc[i][2]);
        }
    }
#pragma unroll
    for (int i = 0; i < 4; ++i) {
        size_t node = node0 + nb + i;
        if (node < (size_t)N) {
            float dv = dinv[node];
#pragma unroll
            for (int jj = 0; jj < 3; ++jj) {
                // col 47 gets 0 (sW pad col is 0) -> true zero pad
                xw2h[node * C48 + c0 + jj] = __float2half_rn(acc[i][jj] * dv);
            }
        } else if (node == (size_t)N) {
#pragma unroll
            for (int jj = 0; jj < 3; ++jj)
                xw2h[node * C48 + c0 + jj] = __float2half_rn(0.f);  // zero row for pads
        }
    }
}

// ---------- agg2: out[n] = b2 + dinv[n] * sum_j xw2[src_j] ----------
// dword (=half2) gather: 24 lanes cover one 96B row exactly; 2 edges per step.

__global__ __launch_bounds__(256) void agg2(const uint32* __restrict__ xw2d,
                                            const int* __restrict__ rowptr,
                                            const int* __restrict__ ep,
                                            const float* __restrict__ dinv,
                                            const float* __restrict__ b2,
                                            float* __restrict__ out) {
    int node = blockIdx.x * 4 + (threadIdx.x >> 6);
    if (node >= N) return;
    int lane = threadIdx.x & 63;
    int hf = lane >> 5;      // which edge of the pair
    int q  = lane & 31;      // dword within row (only q<24 valid)
    bool act = q < 24;
    int beg = rowptr[node], end = rowptr[node + 1];   // cap, multiple of 8
    float a0 = 0.f, a1 = 0.f;
    for (int j = beg; j < end; j += 8) {
        int s0 = ep[j + hf];
        int s1 = ep[j + 2 + hf];
        int s2 = ep[j + 4 + hf];
        int s3 = ep[j + 6 + hf];
        if (act) {
            uint32 v0 = xw2d[(size_t)s0 * 24 + q];
            uint32 v1 = xw2d[(size_t)s1 * 24 + q];
            uint32 v2 = xw2d[(size_t)s2 * 24 + q];
            uint32 v3 = xw2d[(size_t)s3 * 24 + q];
            float2 f;
            f = __half22float2(*(const __half2*)&v0); a0 += f.x; a1 += f.y;
            f = __half22float2(*(const __half2*)&v1); a0 += f.x; a1 += f.y;
            f = __half22float2(*(const __half2*)&v2); a0 += f.x; a1 += f.y;
            f = __half22float2(*(const __half2*)&v3); a0 += f.x; a1 += f.y;
        }
    }
    a0 += __shfl_xor(a0, 32);
    a1 += __shfl_xor(a1, 32);
    if (hf == 0 && act) {
        float dv = dinv[node];
        int c = q * 2;
        out[(size_t)node * C + c] = fmaf(dv, a0, b2[c]);
        if (c + 1 < C) out[(size_t)node * C + c + 1] = fmaf(dv, a1, b2[c + 1]);
    }
}

extern "C" void kernel_launch(void* const* d_in, const int* in_sizes, int n_in,
                              void* d_out, int out_size, void* d_ws, size_t ws_size,
                              hipStream_t stream) {
    const float* x  = (const float*)d_in[0];
    const int*   ei = (const int*)d_in[1];
    const float* W1 = (const float*)d_in[2];
    const float* b1 = (const float*)d_in[3];
    const float* W2 = (const float*)d_in[4];
    const float* b2 = (const float*)d_in[5];
    float* out = (float*)d_out;

    size_t off = 0;
    auto alloc = [&](size_t bytes) {
        void* p = (char*)d_ws + off;
        off += (bytes + 255) & ~(size_t)255;
        return p;
    };
    int*    cnt      = (int*)alloc((size_t)N * 4);
    int*    rowptr   = (int*)alloc((size_t)(N + 1) * 4);
    int*    epos     = (int*)alloc((size_t)E * 4);
    int*    partials = (int*)alloc(64 * 4);
    int*    pscan    = (int*)alloc(64 * 4);
    float*  dinv     = (float*)alloc((size_t)N * 4);
    int*    ep       = (int*)alloc((size_t)EN_CAP * 4);
    uint32* xw8      = (uint32*)alloc((size_t)(N + 1) * 32 * 4);   // fp8 [N+1][128]
    __half* hh       = (__half*)alloc((size_t)N * HD * 2);
    __half* xw2h     = (__half*)alloc((size_t)(N + 1) * C48 * 2);  // fp16 [N+1][48]
    (void)ws_size;

    int gN = (N + 255) / 256;
    int gE = (E + 255) / 256;

    init_cnt<<<gN, 256, 0, stream>>>(cnt);
    count_pos<<<gE, 256, 0, stream>>>(ei + E, cnt, epos);
    scan_pass1<<<NB_SCAN, 256, 0, stream>>>(cnt, partials);
    scan_pass2<<<1, 64, 0, stream>>>(partials, pscan, rowptr);
    scan_pass3<<<NB_SCAN, 256, 0, stream>>>(cnt, pscan, rowptr, dinv, ep);
    scatter_edges<<<gE, 256, 0, stream>>>(ei, rowptr, epos, ep);

    gemm1<<<(N + 63) / 64, 256, 0, stream>>>(x, W1, dinv, xw8);
    agg1<<<(N + 3) / 4, 256, 0, stream>>>(xw8, rowptr, ep, dinv, b1, hh);
    gemm2<<<(N + 63) / 64, 256, 0, stream>>>((const uint32*)hh, W2, dinv, xw2h);
    agg2<<<(N + 3) / 4, 256, 0, stream>>>((const uint32*)xw2h, rowptr, ep, dinv, b2, out);
}

// Round 5
// 325.785 us; speedup vs baseline: 1.3605x; 1.1267x over previous
//
#include <hip/hip_runtime.h>
#include <hip/hip_fp16.h>

// GCN 2-layer inference, N=100000, E=1600000, F_IN=100, H=128, C=47.
// R8: atomic-free bucketed CSR build. R7's profile: count_pos #1 at 67us with
// WRITE_SIZE=56MB == 1.6M x 32B sector write-throughs (device-scope atomic RMW
// resolves memory-side on multi-XCD). scatter_edges had the same disease
// (random 4B writes -> 1 sector/edge). Replaced both with a dst-bucket
// pipeline (196 buckets x 512 nodes): per-block LDS histograms + two tiny
// scans + dense bucket scatter + per-bucket LDS-atomic count/place.
// scan_pass1/2/3 (rowptr/dinv/selfloop/pads) and all GEMM/agg kernels are
// unchanged from R7 (367us, absmax 0.0078 vs thr 0.0126).

typedef unsigned int uint32;
typedef float f32x2 __attribute__((ext_vector_type(2)));
typedef __fp16 fp16x2 __attribute__((ext_vector_type(2)));
typedef _Float16 h2v __attribute__((ext_vector_type(2)));

constexpr int N    = 100000;
constexpr int E    = 1600000;
constexpr int FIN  = 100;
constexpr int HD   = 128;
constexpr int C    = 47;
constexpr int C48  = 48;
constexpr int EN_CAP = E + 8 * N;    // padded edge-slot upper bound
constexpr int SCAN_CHUNK = 2048;     // 256 threads * 8
constexpr int NB_SCAN = (N + SCAN_CHUNK - 1) / SCAN_CHUNK;  // 49

// bucketed CSR build
constexpr int NPB   = 512;                          // nodes per bucket (dst>>9)
constexpr int NBUCK = (N + NPB - 1) / NPB;          // 196
constexpr int ABLK  = 400;                          // A-phase blocks
constexpr int EPB   = E / ABLK;                     // 4000 edges per A-block

// ---------- fp8 / fp16 helpers ----------

__device__ __forceinline__ uint32 pack_fp8x4(float x, float y, float z, float w) {
    int r = __builtin_amdgcn_cvt_pk_fp8_f32(x, y, 0, false);   // bytes 0,1
    r = __builtin_amdgcn_cvt_pk_fp8_f32(z, w, r, true);        // bytes 2,3
    return (uint32)r;
}

__device__ __forceinline__ void acc_fp8x4(uint32 v, float& a0, float& a1,
                                          float& a2, float& a3) {
    f32x2 lo = __builtin_amdgcn_cvt_pk_f32_fp8((int)v, false);
    f32x2 hi = __builtin_amdgcn_cvt_pk_f32_fp8((int)v, true);
    a0 += lo[0]; a1 += lo[1]; a2 += hi[0]; a3 += hi[1];
}

__device__ __forceinline__ uint32 pk16(float a, float b) {
    union { fp16x2 h; uint32 u; } x;
    x.h = __builtin_amdgcn_cvt_pkrtz(a, b);    // v_cvt_pkrtz_f16_f32
    return x.u;
}

__device__ __forceinline__ float dot2f(uint32 a, uint32 b, float c) {
#if defined(__has_builtin) && __has_builtin(__builtin_amdgcn_fdot2)
    union { uint32 u; h2v h; } xa, xb; xa.u = a; xb.u = b;
    return __builtin_amdgcn_fdot2(xa.h, xb.h, c, false);
#else
    union { uint32 u; __half2 h; } xa, xb; xa.u = a; xb.u = b;
    float2 fa = __half22float2(xa.h), fb = __half22float2(xb.h);
    return fmaf(fa.y, fb.y, fmaf(fa.x, fb.x, c));
#endif
}

// ---------- bucketed CSR build (no global atomics) ----------

// A1: per-block bucket histogram -> blockhist[bucket][block]
__global__ __launch_bounds__(256) void bucket_hist(const int* __restrict__ dst,
                                                   int* __restrict__ blockhist) {
    __shared__ int h[NBUCK];
    int t = threadIdx.x, blk = blockIdx.x;
    for (int i = t; i < NBUCK; i += 256) h[i] = 0;
    __syncthreads();
    int base = blk * EPB;
    for (int i = t; i < EPB; i += 256)
        atomicAdd(&h[dst[base + i] >> 9], 1);
    __syncthreads();
    for (int i = t; i < NBUCK; i += 256) blockhist[i * ABLK + blk] = h[i];
}

// S1a: per-bucket exclusive scan over the 400 block entries (in place);
// bucket total -> bcnt[b]
__global__ __launch_bounds__(256) void scan_blocks(int* __restrict__ blockhist,
                                                   int* __restrict__ bcnt) {
    __shared__ int sm[512];
    int b = blockIdx.x, t = threadIdx.x;
    int v0 = (t       < ABLK) ? blockhist[b * ABLK + t] : 0;
    int v1 = (t + 256 < ABLK) ? blockhist[b * ABLK + t + 256] : 0;
    sm[t] = v0; sm[t + 256] = v1;
    __syncthreads();
    for (int off = 1; off < 512; off <<= 1) {
        int o0 = sm[t], o1 = sm[t + 256];
        int a0 = (t >= off) ? sm[t - off] : 0;
        int a1 = (t + 256 >= off) ? sm[t + 256 - off] : 0;
        __syncthreads();
        sm[t] = o0 + a0; sm[t + 256] = o1 + a1;
        __syncthreads();
    }
    if (t < ABLK)       blockhist[b * ABLK + t]       = sm[t] - v0;        // exclusive
    if (t + 256 < ABLK) blockhist[b * ABLK + t + 256] = sm[t + 256] - v1;
    if (t == 0) bcnt[b] = sm[ABLK - 1];
}

// S1b: exclusive scan over 196 bucket totals
__global__ void scan_buckets(const int* __restrict__ bcnt, int* __restrict__ bbase) {
    if (threadIdx.x == 0) {
        int run = 0;
        for (int i = 0; i < NBUCK; ++i) { bbase[i] = run; run += bcnt[i]; }
        bbase[NBUCK] = run;   // == E
    }
}

// A2: place packed (dstLocal<<20 | src) into dense bucket segments
__global__ __launch_bounds__(256) void bucket_scatter(const int* __restrict__ ei,
                                                      const int* __restrict__ blockhist,
                                                      const int* __restrict__ bbase,
                                                      uint32* __restrict__ pairs) {
    __shared__ int baseL[NBUCK];
    __shared__ int cur[NBUCK];
    int t = threadIdx.x, blk = blockIdx.x;
    for (int i = t; i < NBUCK; i += 256) {
        baseL[i] = bbase[i] + blockhist[i * ABLK + blk];
        cur[i] = 0;
    }
    __syncthreads();
    int base = blk * EPB;
    for (int i = t; i < EPB; i += 256) {
        int s = ei[base + i];
        int d = ei[E + base + i];
        int b = d >> 9;
        int off = atomicAdd(&cur[b], 1);
        pairs[baseL[b] + off] = (uint32)s | ((uint32)(d & (NPB - 1)) << 20);
    }
}

// B1: per-bucket node degree count (LDS atomics) -> cnt[] (1 = self loop)
__global__ __launch_bounds__(256) void bucket_count(const uint32* __restrict__ pairs,
                                                    const int* __restrict__ bbase,
                                                    int* __restrict__ cnt) {
    __shared__ int c[NPB];
    int b = blockIdx.x, t = threadIdx.x;
    for (int i = t; i < NPB; i += 256) c[i] = 1;   // self loop
    __syncthreads();
    int beg = bbase[b], end = bbase[b + 1];
    for (int i = beg + t; i < end; i += 256)
        atomicAdd(&c[pairs[i] >> 20], 1);
    __syncthreads();
    int node0 = b * NPB;
    for (int i = t; i < NPB; i += 256) {
        int n = node0 + i;
        if (n < N) cnt[n] = c[i];
    }
}

// B2: per-bucket slot placement; ep writes stay inside the bucket's CSR range
__global__ __launch_bounds__(256) void bucket_place(const uint32* __restrict__ pairs,
                                                    const int* __restrict__ bbase,
                                                    const int* __restrict__ rowptr,
                                                    int* __restrict__ ep) {
    __shared__ int rowL[NPB];
    __shared__ int cur[NPB];
    int b = blockIdx.x, t = threadIdx.x;
    int node0 = b * NPB;
    for (int i = t; i < NPB; i += 256) {
        int n = node0 + i;
        rowL[i] = (n < N) ? rowptr[n] : 0;
        cur[i] = 1;   // slot 0 = self loop (written by scan_pass3)
    }
    __syncthreads();
    int beg = bbase[b], end = bbase[b + 1];
    for (int i = beg + t; i < end; i += 256) {
        uint32 p = pairs[i];
        int dl = p >> 20;
        int slot = atomicAdd(&cur[dl], 1);
        ep[rowL[dl] + slot] = (int)(p & 0xFFFFF);
    }
}

// ---------- global scan over node capacities (unchanged from R7) ----------

// sums CAPACITIES: cap = deg rounded up to multiple of 8
__global__ void scan_pass1(const int* __restrict__ cnt, int* __restrict__ partials) {
    int t = threadIdx.x, b = blockIdx.x;
    int base = b * SCAN_CHUNK + t * 8;
    int s = 0;
#pragma unroll
    for (int i = 0; i < 8; ++i) {
        int idx = base + i;
        if (idx < N) s += (cnt[idx] + 7) & ~7;
    }
    __shared__ int sm[256];
    sm[t] = s;
    __syncthreads();
    for (int off = 128; off > 0; off >>= 1) {
        if (t < off) sm[t] += sm[t + off];
        __syncthreads();
    }
    if (t == 0) partials[b] = sm[0];
}

__global__ void scan_pass2(const int* __restrict__ partials, int* __restrict__ pscan,
                           int* __restrict__ rowptr) {
    if (threadIdx.x == 0) {
        int run = 0;
        for (int i = 0; i < NB_SCAN; ++i) { pscan[i] = run; run += partials[i]; }
        rowptr[N] = run;   // padded total, <= E + 8N
    }
}

// rowptr (cap-based) + dinv + self-loop slot + pad slots (src=N -> zero row)
__global__ void scan_pass3(const int* __restrict__ cnt, const int* __restrict__ pscan,
                           int* __restrict__ rowptr, float* __restrict__ dinv,
                           int* __restrict__ ep) {
    int t = threadIdx.x, b = blockIdx.x;
    int base = b * SCAN_CHUNK + t * 8;
    int v[8];
    int s = 0;
#pragma unroll
    for (int i = 0; i < 8; ++i) {
        int idx = base + i;
        v[i] = (idx < N) ? cnt[idx] : 0;
        s += (v[i] + 7) & ~7;
    }
    __shared__ int sm[256];
    sm[t] = s;
    __syncthreads();
    for (int off = 1; off < 256; off <<= 1) {
        int tv = (t >= off) ? sm[t - off] : 0;
        __syncthreads();
        sm[t] += tv;
        __syncthreads();
    }
    int excl = sm[t] - s + pscan[b];
#pragma unroll
    for (int i = 0; i < 8; ++i) {
        int idx = base + i;
        if (idx < N) {
            int cap = (v[i] + 7) & ~7;
            rowptr[idx] = excl;
            ep[excl] = idx;                  // self loop at slot 0
            dinv[idx] = rsqrtf((float)v[i]); // true degree (>=1)
            for (int k = v[i]; k < cap; ++k) ep[excl + k] = N;  // pads -> zero row
            excl += cap;
        }
    }
}

// ---------- GEMM1: xw8[N+1,32 dwords] fp8 = dinv[n] * (x[N,100] @ W1[100,128]) ----------
// fp16 operands in LDS, v_dot2 inner loop. K=100 = 50 exact k-pairs.

__global__ __launch_bounds__(256) void gemm1(const float* __restrict__ x,
                                             const float* __restrict__ W1,
                                             const float* __restrict__ dinv,
                                             uint32* __restrict__ xw8) {
    __shared__ uint32 sW[50 * 128];    // 25.6 KB
    __shared__ uint32 sX[64 * 50];     // 12.8 KB
    int tx = threadIdx.x;
    size_t node0 = (size_t)blockIdx.x * 64;

    for (int i = tx; i < 50 * 128; i += 256) {
        int kk = i >> 7, c = i & 127;
        sW[i] = pk16(W1[(2 * kk) * HD + c], W1[(2 * kk + 1) * HD + c]);
    }
    for (int i = tx; i < 64 * 50; i += 256) {
        int row = i / 50, kk = i - row * 50;
        size_t node = node0 + row;
        float2 ab = make_float2(0.f, 0.f);
        if (node < (size_t)N)
            ab = ((const float2*)(x + node * FIN))[kk];   // 8B aligned (400B rows)
        sX[i] = pk16(ab.x, ab.y);
    }
    __syncthreads();

    int col = (tx & 31) * 4;        // 0..124
    int nb  = (tx >> 5) * 8;        // 0..56
    float4 acc[8];
#pragma unroll
    for (int i = 0; i < 8; ++i) acc[i] = make_float4(0.f, 0.f, 0.f, 0.f);

    for (int kk = 0; kk < 50; ++kk) {
        uint4 w = *(const uint4*)&sW[kk * 128 + col];     // ds_read_b128
#pragma unroll
        for (int i = 0; i < 8; ++i) {
            uint32 a = sX[(nb + i) * 50 + kk];
            acc[i].x = dot2f(a, w.x, acc[i].x);
            acc[i].y = dot2f(a, w.y, acc[i].y);
            acc[i].z = dot2f(a, w.z, acc[i].z);
            acc[i].w = dot2f(a, w.w, acc[i].w);
        }
    }
#pragma unroll
    for (int i = 0; i < 8; ++i) {
        size_t node = node0 + nb + i;
        if (node < (size_t)N) {
            float dv = dinv[node];
            xw8[node * 32 + (col >> 2)] =
                pack_fp8x4(acc[i].x * dv, acc[i].y * dv, acc[i].z * dv, acc[i].w * dv);
        } else if (node == (size_t)N) {
            xw8[node * 32 + (col >> 2)] = 0u;   // zero row for pad edges
        }
    }
}

// ---------- agg1: h[n] (fp16) = relu(b1 + dinv[n] * sum_j xw8[src_j]) ----------

__global__ __launch_bounds__(256) void agg1(const uint32* __restrict__ xw8,
                                            const int* __restrict__ rowptr,
                                            const int* __restrict__ ep,
                                            const float* __restrict__ dinv,
                                            const float* __restrict__ b1,
                                            __half* __restrict__ h) {
    int node = blockIdx.x * 4 + (threadIdx.x >> 6);
    if (node >= N) return;
    int lane = threadIdx.x & 63;
    int hf = lane >> 5;      // which edge of the pair
    int q  = lane & 31;      // dword within 128B row -> dims q*4..q*4+3
    int beg = rowptr[node], end = rowptr[node + 1];   // cap, multiple of 8
    float a0 = 0.f, a1 = 0.f, a2 = 0.f, a3 = 0.f;
    for (int j = beg; j < end; j += 8) {
        int s0 = ep[j + hf];
        int s1 = ep[j + 2 + hf];
        int s2 = ep[j + 4 + hf];
        int s3 = ep[j + 6 + hf];
        uint32 v0 = xw8[(size_t)s0 * 32 + q];
        uint32 v1 = xw8[(size_t)s1 * 32 + q];
        uint32 v2 = xw8[(size_t)s2 * 32 + q];
        uint32 v3 = xw8[(size_t)s3 * 32 + q];
        acc_fp8x4(v0, a0, a1, a2, a3);
        acc_fp8x4(v1, a0, a1, a2, a3);
        acc_fp8x4(v2, a0, a1, a2, a3);
        acc_fp8x4(v3, a0, a1, a2, a3);
    }
    a0 += __shfl_xor(a0, 32);
    a1 += __shfl_xor(a1, 32);
    a2 += __shfl_xor(a2, 32);
    a3 += __shfl_xor(a3, 32);
    if (hf == 0) {
        float dv = dinv[node];
        float4 bb = *(const float4*)&b1[q * 4];
        float r0 = fmaxf(fmaf(dv, a0, bb.x), 0.f);
        float r1 = fmaxf(fmaf(dv, a1, bb.y), 0.f);
        float r2 = fmaxf(fmaf(dv, a2, bb.z), 0.f);
        float r3 = fmaxf(fmaf(dv, a3, bb.w), 0.f);
        union { __half2 h2[2]; uint2 u; } p;
        p.h2[0] = __floats2half2_rn(r0, r1);
        p.h2[1] = __floats2half2_rn(r2, r3);
        *(uint2*)&h[(size_t)node * HD + q * 4] = p.u;
    }
}

// ---------- GEMM2: xw2h[N+1,48] fp16 = dinv[n] * (h[N,128] @ W2[128,47]), col47=0 ----------

__global__ __launch_bounds__(256) void gemm2(const uint32* __restrict__ hh,
                                             const float* __restrict__ W2,
                                             const float* __restrict__ dinv,
                                             __half* __restrict__ xw2h) {
    __shared__ uint32 sW[64 * 48];     // 12.3 KB
    __shared__ uint32 sH[64 * 66];     // 16.9 KB (pad 66)
    int tx = threadIdx.x;
    size_t node0 = (size_t)blockIdx.x * 64;

    for (int i = tx; i < 64 * 48; i += 256) {
        int kk = i / 48, c = i - kk * 48;
        float a = 0.f, b = 0.f;
        if (c < C) {
            a = W2[(2 * kk) * C + c];
            b = W2[(2 * kk + 1) * C + c];
        }
        sW[i] = pk16(a, b);
    }
    for (int i = tx; i < 64 * 64; i += 256) {
        int row = i >> 6, kk = i & 63;
        size_t g = node0 * 64 + i;
        sH[row * 66 + kk] = (g < (size_t)N * 64) ? hh[g] : 0u;
    }
    __syncthreads();

    int c0 = (tx & 15) * 3;        // 0..45
    int nb = (tx >> 4) * 4;        // 0..60
    float acc[4][3] = {};
    for (int kk = 0; kk < 64; ++kk) {
        uint32 w0 = sW[kk * 48 + c0];
        uint32 w1 = sW[kk * 48 + c0 + 1];
        uint32 w2 = sW[kk * 48 + c0 + 2];
#pragma unroll
        for (int i = 0; i < 4; ++i) {
            uint32 a = sH[(nb + i) * 66 + kk];
            acc[i][0] = dot2f(a, w0, acc[i][0]);
            acc[i][1] = dot2f(a, w1, acc[i][1]);
            acc[i][2] = dot2f(a, w2, acc[i][2]);
        }
    }
#pragma unroll
    for (int i = 0; i < 4; ++i) {
        size_t node = node0 + nb + i;
        if (node < (size_t)N) {
            float dv = dinv[node];
#pragma unroll
            for (int jj = 0; jj < 3; ++jj) {
                // col 47 gets 0 (sW pad col is 0) -> true zero pad
                xw2h[node * C48 + c0 + jj] = __float2half_rn(acc[i][jj] * dv);
            }
        } else if (node == (size_t)N) {
#pragma unroll
            for (int jj = 0; jj < 3; ++jj)
                xw2h[node * C48 + c0 + jj] = __float2half_rn(0.f);  // zero row for pads
        }
    }
}

// ---------- agg2: out[n] = b2 + dinv[n] * sum_j xw2[src_j] ----------
// dword (=half2) gather: 24 lanes cover one 96B row exactly; 2 edges per step.

__global__ __launch_bounds__(256) void agg2(const uint32* __restrict__ xw2d,
                                            const int* __restrict__ rowptr,
                                            const int* __restrict__ ep,
                                            const float* __restrict__ dinv,
                                            const float* __restrict__ b2,
                                            float* __restrict__ out) {
    int node = blockIdx.x * 4 + (threadIdx.x >> 6);
    if (node >= N) return;
    int lane = threadIdx.x & 63;
    int hf = lane >> 5;      // which edge of the pair
    int q  = lane & 31;      // dword within row (only q<24 valid)
    bool act = q < 24;
    int beg = rowptr[node], end = rowptr[node + 1];   // cap, multiple of 8
    float a0 = 0.f, a1 = 0.f;
    for (int j = beg; j < end; j += 8) {
        int s0 = ep[j + hf];
        int s1 = ep[j + 2 + hf];
        int s2 = ep[j + 4 + hf];
        int s3 = ep[j + 6 + hf];
        if (act) {
            uint32 v0 = xw2d[(size_t)s0 * 24 + q];
            uint32 v1 = xw2d[(size_t)s1 * 24 + q];
            uint32 v2 = xw2d[(size_t)s2 * 24 + q];
            uint32 v3 = xw2d[(size_t)s3 * 24 + q];
            float2 f;
            f = __half22float2(*(const __half2*)&v0); a0 += f.x; a1 += f.y;
            f = __half22float2(*(const __half2*)&v1); a0 += f.x; a1 += f.y;
            f = __half22float2(*(const __half2*)&v2); a0 += f.x; a1 += f.y;
            f = __half22float2(*(const __half2*)&v3); a0 += f.x; a1 += f.y;
        }
    }
    a0 += __shfl_xor(a0, 32);
    a1 += __shfl_xor(a1, 32);
    if (hf == 0 && act) {
        float dv = dinv[node];
        int c = q * 2;
        out[(size_t)node * C + c] = fmaf(dv, a0, b2[c]);
        if (c + 1 < C) out[(size_t)node * C + c + 1] = fmaf(dv, a1, b2[c + 1]);
    }
}

extern "C" void kernel_launch(void* const* d_in, const int* in_sizes, int n_in,
                              void* d_out, int out_size, void* d_ws, size_t ws_size,
                              hipStream_t stream) {
    const float* x  = (const float*)d_in[0];
    const int*   ei = (const int*)d_in[1];
    const float* W1 = (const float*)d_in[2];
    const float* b1 = (const float*)d_in[3];
    const float* W2 = (const float*)d_in[4];
    const float* b2 = (const float*)d_in[5];
    float* out = (float*)d_out;

    size_t off = 0;
    auto alloc = [&](size_t bytes) {
        void* p = (char*)d_ws + off;
        off += (bytes + 255) & ~(size_t)255;
        return p;
    };
    int*    cnt       = (int*)alloc((size_t)N * 4);
    int*    rowptr    = (int*)alloc((size_t)(N + 1) * 4);
    int*    blockhist = (int*)alloc((size_t)NBUCK * ABLK * 4);
    int*    bcnt      = (int*)alloc((size_t)NBUCK * 4);
    int*    bbase     = (int*)alloc((size_t)(NBUCK + 1) * 4);
    uint32* pairs     = (uint32*)alloc((size_t)E * 4);
    int*    partials  = (int*)alloc(64 * 4);
    int*    pscan     = (int*)alloc(64 * 4);
    float*  dinv      = (float*)alloc((size_t)N * 4);
    int*    ep        = (int*)alloc((size_t)EN_CAP * 4);
    uint32* xw8       = (uint32*)alloc((size_t)(N + 1) * 32 * 4);   // fp8 [N+1][128]
    __half* hh        = (__half*)alloc((size_t)N * HD * 2);
    __half* xw2h      = (__half*)alloc((size_t)(N + 1) * C48 * 2);  // fp16 [N+1][48]
    (void)ws_size;

    bucket_hist<<<ABLK, 256, 0, stream>>>(ei + E, blockhist);
    scan_blocks<<<NBUCK, 256, 0, stream>>>(blockhist, bcnt);
    scan_buckets<<<1, 64, 0, stream>>>(bcnt, bbase);
    bucket_scatter<<<ABLK, 256, 0, stream>>>(ei, blockhist, bbase, pairs);
    bucket_count<<<NBUCK, 256, 0, stream>>>(pairs, bbase, cnt);
    scan_pass1<<<NB_SCAN, 256, 0, stream>>>(cnt, partials);
    scan_pass2<<<1, 64, 0, stream>>>(partials, pscan, rowptr);
    scan_pass3<<<NB_SCAN, 256, 0, stream>>>(cnt, pscan, rowptr, dinv, ep);
    bucket_place<<<NBUCK, 256, 0, stream>>>(pairs, bbase, rowptr, ep);

    gemm1<<<(N + 63) / 64, 256, 0, stream>>>(x, W1, dinv, xw8);
    agg1<<<(N + 3) / 4, 256, 0, stream>>>(xw8, rowptr, ep, dinv, b1, hh);
    gemm2<<<(N + 63) / 64, 256, 0, stream>>>((const uint32*)hh, W2, dinv, xw2h);
    agg2<<<(N + 3) / 4, 256, 0, stream>>>((const uint32*)xw2h, rowptr, ep, dinv, b2, out);
}